// Round 13
// baseline (589.273 us; speedup 1.0000x reference)
//
#include <hip/hip_runtime.h>
#include <hip/hip_bf16.h>
#include <math.h>

#define F_IN 128
#define HD   64    // H*D layer1
#define NH   8
#define DH   8
#define NC   7     // classes
#define CAP  64    // fixed CSR row capacity (deg ~ Poisson(32); P(>64)~1.4e-7)
#define OVF_CAP 8192

typedef __attribute__((ext_vector_type(8))) short short8v;  // 8 bf16 (4 VGPR)
typedef __attribute__((ext_vector_type(4))) float f32x4;

__device__ __forceinline__ float lrelu(float e) { return fmaxf(e, 0.2f * e); }
__device__ __forceinline__ ushort f2bf(float f) {
    unsigned u = __float_as_uint(f);
    unsigned rounded = u + 0x7FFF + ((u >> 16) & 1);
    return (ushort)(rounded >> 16);
}

// ---- K0: W1 -> bf16 hi/lo, laid out in MFMA B-fragment order ----------------
__global__ __launch_bounds__(256) void k_wcvt(
    const float* __restrict__ W1, ushort* __restrict__ Wh, ushort* __restrict__ Wl)
{
    int t = threadIdx.x;
    for (int g = t; g < 8192; g += 256) {
        int i = g & 7, lane = (g >> 3) & 63, fs = g >> 9;
        int ct = fs >> 2, ks = fs & 3;
        int k = (ks << 5) + ((lane >> 4) << 3) + i;
        int c = (ct << 4) + (lane & 15);
        float w = W1[k * HD + c];
        ushort wh = f2bf(w);
        float whf = __uint_as_float((uint)wh << 16);
        Wh[g] = wh;
        Wl[g] = f2bf(w - whf);
    }
}

// ---------- K1 fused: MFMA gemm1 (bid%3==0) + CSR scatter (else) -------------
// R11-proven: one-pass fixed-capacity CSR (atomic return = rank, cnt = degree)
// deleted bsum/scan/rowptr/fill.  Sector-write model confirmed: WRITE_SIZE
// 223MB = 3.2M x 32B atomic RMW + 3.2M x 32B csrF stores + outputs.
__global__ __launch_bounds__(256) void k_gemm1h(
    const float* __restrict__ x,
    const ushort* __restrict__ Wh, const ushort* __restrict__ Wl,
    const float* __restrict__ att_src, const float* __restrict__ att_dst,
    ushort* __restrict__ h1b, float* __restrict__ a_src, float* __restrict__ a_dst,
    int N, int GB,
    const int* __restrict__ srcArr, const int* __restrict__ dstArr,
    int* __restrict__ cnt, int* __restrict__ csrF,
    int* __restrict__ ovfn, int* __restrict__ ovf,
    long E)
{
    int t = threadIdx.x;
    int bid = blockIdx.x;

    if (bid % 3 != 0) {
        // ---- scatter branch: grid-stride over edges ----
        long hb = (long)(bid / 3) * 2 + (bid % 3) - 1;    // [0, 2*GB)
        long stride = (long)(2 * GB) * 256;
        for (long i = hb * 256 + t; i < E; i += stride) {
            int d = dstArr[i];
            int s = srcArr[i];
            int idx = atomicAdd(&cnt[d], 1);
            if (idx < CAP) {
                csrF[(size_t)d * CAP + idx] = s;
            } else {
                int o = atomicAdd(ovfn, 1);
                if (o < OVF_CAP) { ovf[2 * o] = d; ovf[2 * o + 1] = s; }
            }
        }
        return;
    }

    int gb = bid / 3;                                     // [0, GB)
    int lane = t & 63;
    int wave = t >> 6;
    int base = gb * 64 + wave * 16;                       // this wave: 16 rows
    if (base >= N) return;                                // wave-uniform exit

    int arow = base + (lane & 15);                        // A-frag row
    if (arow >= N) arow = N - 1;                          // clamp (stores guarded)
    int kg = lane >> 4;                                   // k-group

    f32x4 acc[4];
    #pragma unroll
    for (int ct = 0; ct < 4; ++ct) acc[ct] = (f32x4){0.f, 0.f, 0.f, 0.f};

    #pragma unroll
    for (int ks = 0; ks < 4; ++ks) {
        const float* xp = x + (size_t)arow * F_IN + ks * 32 + kg * 8;
        float4 xa = *(const float4*)xp;
        float4 xb = *(const float4*)(xp + 4);
        float xs[8] = {xa.x, xa.y, xa.z, xa.w, xb.x, xb.y, xb.z, xb.w};
        short8v ah, al;
        #pragma unroll
        for (int i = 0; i < 8; ++i) {
            ushort hh = f2bf(xs[i]);
            ah[i] = (short)hh;
            float hf = __uint_as_float((uint)hh << 16);
            al[i] = (short)f2bf(xs[i] - hf);
        }
        #pragma unroll
        for (int ct = 0; ct < 4; ++ct) {
            size_t fo = (size_t)((ct * 4 + ks) * 64 + lane) * 8;
            short8v bh = *(const short8v*)(Wh + fo);
            short8v bl = *(const short8v*)(Wl + fo);
            acc[ct] = __builtin_amdgcn_mfma_f32_16x16x32_bf16(ah, bh, acc[ct], 0, 0, 0);
            acc[ct] = __builtin_amdgcn_mfma_f32_16x16x32_bf16(al, bh, acc[ct], 0, 0, 0);
            acc[ct] = __builtin_amdgcn_mfma_f32_16x16x32_bf16(ah, bl, acc[ct], 0, 0, 0);
        }
    }

    // epilogue: D lane mapping col = ct*16 + (lane&15), row = base + 4*(lane>>4)+r
    int rg = lane >> 4;
    int cl = lane & 15;
    #pragma unroll
    for (int ct = 0; ct < 4; ++ct) {
        int c = ct * 16 + cl;
        float asv = att_src[c];
        float adv = att_dst[c];
        #pragma unroll
        for (int r = 0; r < 4; ++r) {
            int row = base + rg * 4 + r;
            float v = acc[ct][r];
            if (row < N) h1b[(size_t)row * HD + c] = f2bf(v);
            float vs = v * asv;
            float vd = v * adv;
            vs += __shfl_xor(vs, 1, 64); vd += __shfl_xor(vd, 1, 64);
            vs += __shfl_xor(vs, 2, 64); vd += __shfl_xor(vd, 2, 64);
            vs += __shfl_xor(vs, 4, 64); vd += __shfl_xor(vd, 4, 64);
            if ((lane & 7) == 0 && row < N) {
                int head = 2 * ct + ((lane >> 3) & 1);
                a_src[row * NH + head] = vs;
                a_dst[row * NH + head] = vd;
            }
        }
    }
}

// ---------------- K-gather1 v8: ALL loads upfront, consume after -------------
// R8/R11 evidence: per-chunk pipelining (payload 1 iteration ahead) hides only
// ~100cy of a ~700cy L2/L3 round trip -> ~600cy exposed PER CHUNK (4/dst).
// v8: phase1 issues ALL csr index loads, phase2 ALL payload loads (up to 13
// independent loads in flight), phase3 consumes in chunk order with counted
// vmcnt waits.  Latency paid ~once per dst.  Chunk guards (c*8 < m) are
// wave-uniform; boundary lanes clamp sl=d with w=0.  Per-lane FP order
// unchanged (chunks ascending) -> bit-identical.
__global__ __launch_bounds__(256) void k_gather1(
    const int* __restrict__ cnt, const int* __restrict__ csrF,
    const int* __restrict__ ovfn, const int* __restrict__ ovf,
    const ushort* __restrict__ h1b, const float* __restrict__ a_src,
    const float* __restrict__ a_dst, float* __restrict__ agg, int N)
{
    const uint* __restrict__ h1u = (const uint*)h1b;
    int wave = threadIdx.x >> 6, lane = threadIdx.x & 63;
    int d = blockIdx.x * 4 + wave;
    if (d >= N) return;
    int e = lane >> 3;           // edge slot
    int h = lane & 7;            // head; channels 8h..8h+7 = dwords 4h..4h+3

    float adst = a_dst[d * NH + h];
    float ws = __expf(lrelu(a_src[d * NH + h] + adst));   // self-loop weight
    float wsum = (e == 0) ? ws : 0.f;

    float ax0 = 0.f, ay0 = 0.f, ax1 = 0.f, ay1 = 0.f;
    float ax2 = 0.f, ay2 = 0.f, ax3 = 0.f, ay3 = 0.f;
    if (e == 0) {
        size_t b = (size_t)d * 32 + h * 4;
        uint u0 = h1u[b], u1 = h1u[b + 1], u2 = h1u[b + 2], u3 = h1u[b + 3];
        ax0 = ws * __uint_as_float(u0 << 16); ay0 = ws * __uint_as_float(u0 & 0xFFFF0000u);
        ax1 = ws * __uint_as_float(u1 << 16); ay1 = ws * __uint_as_float(u1 & 0xFFFF0000u);
        ax2 = ws * __uint_as_float(u2 << 16); ay2 = ws * __uint_as_float(u2 & 0xFFFF0000u);
        ax3 = ws * __uint_as_float(u3 << 16); ay3 = ws * __uint_as_float(u3 & 0xFFFF0000u);
    }

    int m = cnt[d]; if (m > CAP) m = CAP;    // wave-uniform
    int jb = d * CAP;

    // ---- phase 1: all csr index loads ----
    int sl[8];
    #pragma unroll
    for (int c = 0; c < 8; ++c) {
        int s_ = c * 8 + e;
        sl[c] = (s_ < m) ? csrF[jb + s_] : d;
    }

    // ---- phase 2: all payload loads (independent, in flight together) ----
    float as[8];
    uint u0a[8], u1a[8], u2a[8], u3a[8];
    #pragma unroll
    for (int c = 0; c < 8; ++c) {
        if (c * 8 < m) {                      // wave-uniform guard
            as[c] = a_src[sl[c] * NH + h];
            size_t b = (size_t)sl[c] * 32 + h * 4;
            u0a[c] = h1u[b];     u1a[c] = h1u[b + 1];
            u2a[c] = h1u[b + 2]; u3a[c] = h1u[b + 3];
        }
    }

    // ---- phase 3: consume in chunk order (counted vmcnt waits) ----
    #pragma unroll
    for (int c = 0; c < 8; ++c) {
        if (c * 8 < m) {
            bool v = (c * 8 + e) < m;
            float w = v ? __expf(lrelu(as[c] + adst)) : 0.f;
            wsum += w;
            ax0 += w * __uint_as_float(u0a[c] << 16); ay0 += w * __uint_as_float(u0a[c] & 0xFFFF0000u);
            ax1 += w * __uint_as_float(u1a[c] << 16); ay1 += w * __uint_as_float(u1a[c] & 0xFFFF0000u);
            ax2 += w * __uint_as_float(u2a[c] << 16); ay2 += w * __uint_as_float(u2a[c] & 0xFFFF0000u);
            ax3 += w * __uint_as_float(u3a[c] << 16); ay3 += w * __uint_as_float(u3a[c] & 0xFFFF0000u);
        }
    }

    // ---- overflow entries (expected none; exactness guard) ----
    int no = *ovfn;
    if (no > 0) {
        if (no > OVF_CAP) no = OVF_CAP;
        for (int k2 = 0; k2 < no; ++k2) {
            int od = ovf[2 * k2], os = ovf[2 * k2 + 1];
            if (od == d && e == 0) {
                float w = __expf(lrelu(a_src[os * NH + h] + adst));
                wsum += w;
                size_t bb = (size_t)os * 32 + h * 4;
                uint o0 = h1u[bb], o1 = h1u[bb + 1], o2 = h1u[bb + 2], o3 = h1u[bb + 3];
                ax0 += w * __uint_as_float(o0 << 16); ay0 += w * __uint_as_float(o0 & 0xFFFF0000u);
                ax1 += w * __uint_as_float(o1 << 16); ay1 += w * __uint_as_float(o1 & 0xFFFF0000u);
                ax2 += w * __uint_as_float(o2 << 16); ay2 += w * __uint_as_float(o2 & 0xFFFF0000u);
                ax3 += w * __uint_as_float(o3 << 16); ay3 += w * __uint_as_float(o3 & 0xFFFF0000u);
            }
        }
    }

    // epilogue: reduce over edge slots (xor bits 3..5 keeps h fixed)
    #pragma unroll
    for (int o = 8; o <= 32; o <<= 1) {
        wsum += __shfl_xor(wsum, o, 64);
        ax0 += __shfl_xor(ax0, o, 64); ay0 += __shfl_xor(ay0, o, 64);
        ax1 += __shfl_xor(ax1, o, 64); ay1 += __shfl_xor(ay1, o, 64);
        ax2 += __shfl_xor(ax2, o, 64); ay2 += __shfl_xor(ay2, o, 64);
        ax3 += __shfl_xor(ax3, o, 64); ay3 += __shfl_xor(ay3, o, 64);
    }
    if (e == 0) {
        float winv = 1.f / (wsum + 1e-16f);
        float* op = agg + (size_t)d * HD + h * 8;
        *(float4*)(op)     = make_float4(ax0 * winv, ay0 * winv, ax1 * winv, ay1 * winv);
        *(float4*)(op + 4) = make_float4(ax2 * winv, ay2 * winv, ax3 * winv, ay3 * winv);
    }
}

// ------- K4: emb = agg1+b1 (OUT0); x2 = elu(emb); h2p = x2@W2; a_*2 ----------
__global__ __launch_bounds__(256) void k_node2(
    const float* __restrict__ agg1, const float* __restrict__ b1,
    const float* __restrict__ W2, const float* __restrict__ att_s2,
    const float* __restrict__ att_d2, float* __restrict__ emb_out,
    float* __restrict__ h2p, float* __restrict__ a_src2, float* __restrict__ a_dst2,
    int N)
{
    __shared__ float sW[HD * NC];
    __shared__ float sb[HD];
    __shared__ float sas[NC], sad[NC];
    int t = threadIdx.x;
    for (int i = t; i < HD * NC; i += 256) sW[i] = W2[i];
    if (t < HD) sb[t] = b1[t];
    if (t < NC) { sas[t] = att_s2[t]; sad[t] = att_d2[t]; }
    __syncthreads();
    int n = blockIdx.x * 256 + t;
    if (n >= N) return;
    const float* ag = agg1 + (size_t)n * HD;
    float* eo = emb_out + (size_t)n * HD;
    float acc[NC];
    #pragma unroll
    for (int c = 0; c < NC; ++c) acc[c] = 0.f;
    #pragma unroll 8
    for (int k = 0; k < HD; ++k) {
        float v = ag[k] + sb[k];
        eo[k] = v;
        float xv = v > 0.f ? v : expm1f(v);   // jax.nn.elu
        #pragma unroll
        for (int c = 0; c < NC; ++c) acc[c] += xv * sW[k * NC + c];
    }
    float as = 0.f, ad = 0.f;
    float* hp = h2p + (size_t)n * 8;
    #pragma unroll
    for (int c = 0; c < NC; ++c) {
        hp[c] = acc[c];
        as += acc[c] * sas[c];
        ad += acc[c] * sad[c];
    }
    hp[7] = 0.f;
    a_src2[n] = as;
    a_dst2[n] = ad;
}

// ------- K-gather2 v3: ALL loads upfront (same mechanism as gather1 v8) ------
__global__ __launch_bounds__(256) void k_gather2(
    const int* __restrict__ cnt, const int* __restrict__ csrF,
    const int* __restrict__ ovfn, const int* __restrict__ ovf,
    const float* __restrict__ h2p, const float* __restrict__ a_src2,
    const float* __restrict__ a_dst2, const float* __restrict__ b2,
    float* __restrict__ out, int N)
{
    int t = threadIdx.x;
    int wave = t >> 6, lane = t & 63;
    int g = lane >> 3;           // edge slot 0..7
    int c = lane & 7;            // channel (7 = pad)
    int n = blockIdx.x * 4 + wave;
    if (n >= N) return;
    float ad = a_dst2[n];
    float w = __expf(lrelu(a_src2[n] + ad));   // self-loop
    float acc  = (g == 0) ? w * h2p[(size_t)n * 8 + c] : 0.f;
    float wsum = (g == 0) ? w : 0.f;

    int m = cnt[n]; if (m > CAP) m = CAP;    // wave-uniform
    int jb = n * CAP;

    // phase 1: all csr index loads
    int sl[8];
    #pragma unroll
    for (int ck = 0; ck < 8; ++ck) {
        int s_ = ck * 8 + g;
        sl[ck] = (s_ < m) ? csrF[jb + s_] : n;
    }
    // phase 2: all payloads
    float as[8], hv[8];
    #pragma unroll
    for (int ck = 0; ck < 8; ++ck) {
        if (ck * 8 < m) {
            as[ck] = a_src2[sl[ck]];
            hv[ck] = h2p[(size_t)sl[ck] * 8 + c];
        }
    }
    // phase 3: consume in chunk order
    #pragma unroll
    for (int ck = 0; ck < 8; ++ck) {
        if (ck * 8 < m) {
            bool v = (ck * 8 + g) < m;
            float ww = v ? __expf(lrelu(as[ck] + ad)) : 0.f;
            acc += ww * hv[ck];
            wsum += ww;
        }
    }

    // overflow entries (expected none)
    int no = *ovfn;
    if (no > 0) {
        if (no > OVF_CAP) no = OVF_CAP;
        for (int k2 = 0; k2 < no; ++k2) {
            int od = ovf[2 * k2], os = ovf[2 * k2 + 1];
            if (od == n && g == 0) {
                float ww = __expf(lrelu(a_src2[os] + ad));
                acc += ww * h2p[(size_t)os * 8 + c];
                wsum += ww;
            }
        }
    }

    #pragma unroll
    for (int o = 32; o >= 8; o >>= 1) {
        acc  += __shfl_xor(acc, o, 64);
        wsum += __shfl_xor(wsum, o, 64);
    }
    float l = (c < NC) ? (acc / (wsum + 1e-16f) + b2[c]) : -1e30f;
    float m2 = l;
    #pragma unroll
    for (int o = 4; o > 0; o >>= 1) m2 = fmaxf(m2, __shfl_xor(m2, o, 8));
    float ex = (c < NC) ? __expf(l - m2) : 0.f;
    float s8 = ex;
    #pragma unroll
    for (int o = 4; o > 0; o >>= 1) s8 += __shfl_xor(s8, o, 8);
    if (g == 0 && c < NC) out[(size_t)n * NC + c] = l - m2 - logf(s8);
}

extern "C" void kernel_launch(void* const* d_in, const int* in_sizes, int n_in,
                              void* d_out, int out_size, void* d_ws, size_t ws_size,
                              hipStream_t stream)
{
    const float* x       = (const float*)d_in[0];
    const int*   ei      = (const int*)d_in[1];
    const float* W1      = (const float*)d_in[2];
    const float* att_s1  = (const float*)d_in[3];
    const float* att_d1  = (const float*)d_in[4];
    const float* b1      = (const float*)d_in[5];
    const float* W2      = (const float*)d_in[6];
    const float* att_s2  = (const float*)d_in[7];
    const float* att_d2  = (const float*)d_in[8];
    const float* b2      = (const float*)d_in[9];

    const int  N = in_sizes[0] / F_IN;
    const long E = (long)in_sizes[1] / 2;
    const int* src = ei;
    const int* dst = ei + E;

    const int Npad  = (N + 3) & ~3;

    // ---- workspace layout ----
    int* cnt  = (int*)d_ws;                    // Npad   (zeroed)
    int* ovfn = cnt + Npad;                    // 8 (1 used, zeroed)
    int* ovf  = ovfn + 8;                      // 2*OVF_CAP
    int* csrF = ovf + 2 * OVF_CAP;             // N*CAP
    ushort* h1b   = (ushort*)(csrF + (size_t)N * CAP);  // Npad*64 bf16
    float* a_src1 = (float*)(h1b + (size_t)Npad * HD);  // N*8
    float* a_dst1 = a_src1 + (size_t)N * NH;   // N*8
    float* agg1   = a_dst1 + (size_t)N * NH;   // N*64
    float* h2p    = agg1 + (size_t)N * HD;     // N*8 (padded NC->8)
    float* a_src2 = h2p + (size_t)N * 8;       // Npad
    float* a_dst2 = a_src2 + Npad;             // Npad
    // W1 hi/lo frag buffers alias a_src2 block (written by k_wcvt before gemm,
    // dead before k_node2 writes a_src2; 16K ushorts << Npad*4B)
    ushort* Wh = (ushort*)a_src2;              // 8192 ushort
    ushort* Wl = Wh + 8192;                    // 8192 ushort

    hipMemsetAsync(cnt, 0, (size_t)(Npad + 8) * sizeof(int), stream);

    const int NB = (N + 255) / 256;
    const int GB = (N + 63) / 64;
    dim3 b256(256);

    // W1 -> bf16 hi/lo fragments
    k_wcvt<<<dim3(1), b256, 0, stream>>>(W1, Wh, Wl);

    // fused MFMA node transform + one-pass CSR scatter (independent work)
    k_gemm1h<<<dim3(3 * GB), b256, 0, stream>>>(
        x, Wh, Wl, att_s1, att_d1, h1b, a_src1, a_dst1, N, GB,
        src, dst, cnt, csrF, ovfn, ovf, E);

    // Layer 1 aggregate
    k_gather1<<<dim3((N + 3) / 4), b256, 0, stream>>>(
        cnt, csrF, ovfn, ovf, h1b, a_src1, a_dst1, agg1, N);

    // emb output + layer-2 prologue
    float* emb = (float*)d_out;               // N*64
    float* lsm = emb + (size_t)N * HD;        // N*7
    k_node2<<<dim3(NB), b256, 0, stream>>>(
        agg1, b1, W2, att_s2, att_d2, emb, h2p, a_src2, a_dst2, N);

    // Layer 2 aggregate + fused log_softmax
    k_gather2<<<dim3((N + 3) / 4), b256, 0, stream>>>(
        cnt, csrF, ovfn, ovf, h2p, a_src2, a_dst2, b2, lsm, N);
}